// Round 1
// baseline (79.649 us; speedup 1.0000x reference)
//
#include <hip/hip_runtime.h>
#include <hip/hip_bf16.h>

// Problem constants (fixed by the reference)
#define NPTS 2048      // N == M == 2048
#define QMIX 8
#define LATD 64
#define IT   16        // i-rows per block in the pair kernel

__device__ __forceinline__ float softplus_f(float x) {
    // matches jax.nn.softplus = max(x,0) + log1p(exp(-|x|))
    return fmaxf(x, 0.0f) + log1pf(expf(-fabsf(x)));
}

// One thread per (point, q). Recomputes the 64-wide hidden layer per thread
// (8x redundancy, still ~2 us total) to avoid an extra kernel + ws round-trip.
// Emits 8 floats per (point,q): [A00, A11, A22, 2A01, 2A02, 2A12, w*cos(2pi ph), w*sin(2pi ph)]
__global__ __launch_bounds__(256) void feat_kernel(
    const float* __restrict__ xin, const float* __restrict__ yin,
    const float* __restrict__ W1, const float* __restrict__ b1,
    const float* __restrict__ Ww, const float* __restrict__ bw,
    const float* __restrict__ Wf, const float* __restrict__ bf,
    const float* __restrict__ Ws, const float* __restrict__ bs,
    float* __restrict__ FX, float* __restrict__ FY)
{
    const int tid = blockIdx.x * blockDim.x + threadIdx.x; // 0 .. 2*NPTS*QMIX-1
    const int q = tid & (QMIX - 1);
    const int p = tid >> 3;
    const bool isx = (p < NPTS);
    const float* pts = isx ? xin : yin;
    float* outF = isx ? FX : FY;
    const int pi = isx ? p : (p - NPTS);

    const float p0 = pts[pi * 3 + 0];
    const float p1 = pts[pi * 3 + 1];
    const float p2 = pts[pi * 3 + 2];

    // hidden layer h = selu(W1 @ p + b1)
    float h[LATD];
#pragma unroll
    for (int l = 0; l < LATD; ++l) {
        float z = fmaf(W1[l * 3 + 0], p0,
                  fmaf(W1[l * 3 + 1], p1,
                  fmaf(W1[l * 3 + 2], p2, b1[l])));
        const float sc = 1.0507009873554805f;        // selu scale
        const float sa = 1.7580993408473766f;        // scale * alpha
        h[l] = (z > 0.0f) ? sc * z : sa * expm1f(z);
    }

    // head matvecs for this q: 1 (w) + 3 (f) + 6 (s) dots of length 64
    float zw  = bw[q];
    float zf0 = bf[q * 3 + 0], zf1 = bf[q * 3 + 1], zf2 = bf[q * 3 + 2];
    float zs0 = bs[q * 6 + 0], zs1 = bs[q * 6 + 1], zs2 = bs[q * 6 + 2];
    float zs3 = bs[q * 6 + 3], zs4 = bs[q * 6 + 4], zs5 = bs[q * 6 + 5];
#pragma unroll
    for (int l = 0; l < LATD; ++l) {
        const float hv = h[l];
        zw  = fmaf(Ww[q * LATD + l],           hv, zw);
        zf0 = fmaf(Wf[(q * 3 + 0) * LATD + l], hv, zf0);
        zf1 = fmaf(Wf[(q * 3 + 1) * LATD + l], hv, zf1);
        zf2 = fmaf(Wf[(q * 3 + 2) * LATD + l], hv, zf2);
        zs0 = fmaf(Ws[(q * 6 + 0) * LATD + l], hv, zs0);
        zs1 = fmaf(Ws[(q * 6 + 1) * LATD + l], hv, zs1);
        zs2 = fmaf(Ws[(q * 6 + 2) * LATD + l], hv, zs2);
        zs3 = fmaf(Ws[(q * 6 + 3) * LATD + l], hv, zs3);
        zs4 = fmaf(Ws[(q * 6 + 4) * LATD + l], hv, zs4);
        zs5 = fmaf(Ws[(q * 6 + 5) * LATD + l], hv, zs5);
    }
    const float w  = softplus_f(zw);
    const float f0 = softplus_f(zf0), f1 = softplus_f(zf1), f2 = softplus_f(zf2);
    const float s0 = softplus_f(zs0), s1 = softplus_f(zs1), s2 = softplus_f(zs2);
    const float s3 = softplus_f(zs3), s4 = softplus_f(zs4), s5 = softplus_f(zs5);

    // A = L @ L^T with L = [[s0,0,0],[s1,s2,0],[s3,s4,s5]]
    const float A00 = s0 * s0;
    const float A11 = fmaf(s1, s1, s2 * s2);
    const float A22 = fmaf(s3, s3, fmaf(s4, s4, s5 * s5));
    const float A01 = s0 * s1;
    const float A02 = s0 * s3;
    const float A12 = fmaf(s1, s3, s2 * s4);

    const float ph = fmaf(f0, p0, fmaf(f1, p1, f2 * p2));
    float sn, cs;
    sincosf(6.283185307179586477f * ph, &sn, &cs);

    float* o = outF + ((size_t)pi * QMIX + q) * 8;
    o[0] = A00;
    o[1] = A11;
    o[2] = A22;
    o[3] = 2.0f * A01;
    o[4] = 2.0f * A02;
    o[5] = 2.0f * A12;
    o[6] = w * cs;
    o[7] = w * sn;
}

// Pair kernel: thread owns column j (Y features in registers),
// block covers IT consecutive i rows (X features wave-uniform -> s_load path).
__global__ __launch_bounds__(256) void pair_kernel(
    const float* __restrict__ xin, const float* __restrict__ yin,
    const float* __restrict__ FX, const float* __restrict__ FY,
    float* __restrict__ out)
{
    const int j  = blockIdx.x * 256 + threadIdx.x;
    const int i0 = blockIdx.y * IT;

    // Y-point features -> registers (64 floats), fully static indexing
    float fy[QMIX * 8];
#pragma unroll
    for (int k = 0; k < QMIX * 8; k += 4) {
        const float4 v = *reinterpret_cast<const float4*>(FY + (size_t)j * (QMIX * 8) + k);
        fy[k + 0] = v.x; fy[k + 1] = v.y; fy[k + 2] = v.z; fy[k + 3] = v.w;
    }
    const float y0 = yin[j * 3 + 0];
    const float y1 = yin[j * 3 + 1];
    const float y2 = yin[j * 3 + 2];

    const float C_EXP = (float)(-2.2360679774997896964 * 1.4426950408889634074); // -sqrt5*log2(e)
    const float SQ5   = 2.2360679774997896964f;
    const float THIRD = 0.3333333333333333f;

    for (int ii = 0; ii < IT; ++ii) {
        const int i = i0 + ii;
        const float d0 = y0 - xin[i * 3 + 0];
        const float d1 = y1 - xin[i * 3 + 1];
        const float d2 = y2 - xin[i * 3 + 2];
        const float p00 = d0 * d0, p11 = d1 * d1, p22 = d2 * d2;
        const float p01 = d0 * d1, p02 = d0 * d2, p12 = d1 * d2;
        const float* __restrict__ cx = FX + (size_t)i * (QMIX * 8); // wave-uniform
        float acc = 0.0f;
#pragma unroll
        for (int q = 0; q < QMIX; ++q) {
            const float* __restrict__ c = cx + q * 8;
            const float qx = fmaf(c[0], p00, fmaf(c[1], p11, fmaf(c[2], p22,
                             fmaf(c[3], p01, fmaf(c[4], p02, c[5] * p12)))));
            const float qy = fmaf(fy[q*8+0], p00, fmaf(fy[q*8+1], p11, fmaf(fy[q*8+2], p22,
                             fmaf(fy[q*8+3], p01, fmaf(fy[q*8+4], p02, fy[q*8+5] * p12)))));
            const float r    = qx + qy;
            const float t    = SQ5 * r;
            const float poly = fmaf(t, fmaf(t, THIRD, 1.0f), 1.0f); // 1 + t + t^2/3
            const float e    = exp2f(C_EXP * r);                    // exp(-sqrt5*r)
            const float ct   = fmaf(c[6], fy[q*8+6], c[7] * fy[q*8+7]);
            acc = fmaf(poly * e, ct, acc);
        }
        out[(size_t)i * NPTS + j] = acc;
    }
}

extern "C" void kernel_launch(void* const* d_in, const int* in_sizes, int n_in,
                              void* d_out, int out_size, void* d_ws, size_t ws_size,
                              hipStream_t stream) {
    const float* x  = (const float*)d_in[0];
    const float* y  = (const float*)d_in[1];
    const float* W1 = (const float*)d_in[2];
    const float* b1 = (const float*)d_in[3];
    const float* Ww = (const float*)d_in[4];
    const float* bw = (const float*)d_in[5];
    const float* Wf = (const float*)d_in[6];
    const float* bf = (const float*)d_in[7];
    const float* Ws = (const float*)d_in[8];
    const float* bs = (const float*)d_in[9];
    float* out = (float*)d_out;

    float* FX = (float*)d_ws;                       // NPTS * 64 floats
    float* FY = FX + (size_t)NPTS * (QMIX * 8);     // NPTS * 64 floats

    // features: 2*NPTS points * QMIX threads each
    feat_kernel<<<dim3((2 * NPTS * QMIX) / 256), dim3(256), 0, stream>>>(
        x, y, W1, b1, Ww, bw, Wf, bf, Ws, bs, FX, FY);

    // pairwise: grid (M/256 columns, N/IT row-tiles)
    pair_kernel<<<dim3(NPTS / 256, NPTS / IT), dim3(256), 0, stream>>>(
        x, y, FX, FY, out);
}

// Round 2
// 65.109 us; speedup vs baseline: 1.2233x; 1.2233x over previous
//
#include <hip/hip_runtime.h>
#include <hip/hip_bf16.h>

#define NPTS 2048      // N == M == 2048
#define QMIX 8
#define LATD 64
#define IT   16        // i-rows per pair block
#define JT   64        // j-columns per pair block
#define QG   4         // q-groups (one per wave)
#define QPG  2         // q per group

__device__ __forceinline__ float softplus_f(float x) {
    return fmaxf(x, 0.0f) + log1pf(expf(-fabsf(x)));
}
__device__ __forceinline__ float selu_f(float z) {
    const float sc = 1.0507009873554805f;   // selu scale
    const float sa = 1.7580993408473766f;   // scale * alpha
    return (z > 0.0f) ? sc * z : sa * expm1f(z);
}

// One thread per (point, q, head-element e). e=0 -> w, e=1..3 -> f, e=4..9 -> s.
// Hidden layer recomputed streaming per thread (no h[] array). Phase 2 (first
// 64 threads) assembles [A00,A11,A22,2A01,2A02,2A12, w*cos, w*sin] per (point,q).
__global__ __launch_bounds__(640) void feat_kernel(
    const float* __restrict__ xin, const float* __restrict__ yin,
    const float* __restrict__ W1, const float* __restrict__ b1,
    const float* __restrict__ Ww, const float* __restrict__ bw,
    const float* __restrict__ Wf, const float* __restrict__ bf,
    const float* __restrict__ Ws, const float* __restrict__ bs,
    float* __restrict__ FX, float* __restrict__ FY)
{
    __shared__ float raw[8 * 80];          // [point_local][q*10+e]
    const int t   = threadIdx.x;
    const int pl  = t / 80;
    const int rem = t % 80;
    const int q   = rem / 10;
    const int e   = rem % 10;
    const int g   = blockIdx.x * 8 + pl;   // global point 0..4095
    const bool isx = (g < NPTS);
    const float* pts = isx ? (xin + 3 * g) : (yin + 3 * (g - NPTS));
    const float p0 = pts[0], p1 = pts[1], p2 = pts[2];

    const float* row;
    float acc;
    if (e == 0)      { row = Ww + q * LATD;                 acc = bw[q]; }
    else if (e <= 3) { row = Wf + (q * 3 + (e - 1)) * LATD; acc = bf[q * 3 + (e - 1)]; }
    else             { row = Ws + (q * 6 + (e - 4)) * LATD; acc = bs[q * 6 + (e - 4)]; }

#pragma unroll
    for (int l4 = 0; l4 < LATD / 4; ++l4) {
        const float4 rv = reinterpret_cast<const float4*>(row)[l4];
#pragma unroll
        for (int u = 0; u < 4; ++u) {
            const int l = l4 * 4 + u;
            const float z = fmaf(W1[l * 3 + 0], p0,
                            fmaf(W1[l * 3 + 1], p1,
                            fmaf(W1[l * 3 + 2], p2, b1[l])));
            const float rr = (u == 0) ? rv.x : (u == 1) ? rv.y : (u == 2) ? rv.z : rv.w;
            acc = fmaf(rr, selu_f(z), acc);
        }
    }
    raw[t] = softplus_f(acc);
    __syncthreads();

    if (t < 64) {
        const int pl2 = t / 8, q2 = t % 8;
        const int g2  = blockIdx.x * 8 + pl2;
        const bool isx2 = (g2 < NPTS);
        const float* pts2 = isx2 ? (xin + 3 * g2) : (yin + 3 * (g2 - NPTS));
        const float c0 = pts2[0], c1 = pts2[1], c2 = pts2[2];
        const float* r = raw + pl2 * 80 + q2 * 10;
        const float w  = r[0];
        const float f0 = r[1], f1 = r[2], f2 = r[3];
        const float s0 = r[4], s1 = r[5], s2 = r[6];
        const float s3 = r[7], s4 = r[8], s5 = r[9];

        // A = L L^T, L = [[s0,0,0],[s1,s2,0],[s3,s4,s5]]
        const float A00 = s0 * s0;
        const float A11 = fmaf(s1, s1, s2 * s2);
        const float A22 = fmaf(s3, s3, fmaf(s4, s4, s5 * s5));
        const float A01 = s0 * s1;
        const float A02 = s0 * s3;
        const float A12 = fmaf(s1, s3, s2 * s4);
        const float ph  = fmaf(f0, c0, fmaf(f1, c1, f2 * c2));
        float sn, cs;
        sincosf(6.283185307179586477f * ph, &sn, &cs);

        float* outF = isx2 ? FX : FY;
        const int pi = isx2 ? g2 : (g2 - NPTS);
        float* o = outF + ((size_t)pi * QMIX + q2) * 8;
        float4 v0 = make_float4(A00, A11, A22, 2.0f * A01);
        float4 v1 = make_float4(2.0f * A02, 2.0f * A12, w * cs, w * sn);
        reinterpret_cast<float4*>(o)[0] = v0;
        reinterpret_cast<float4*>(o)[1] = v1;
    }
}

// Pair kernel, q-split: wave qg owns q = {2qg, 2qg+1}; lanes own j columns.
// acc[IT] per thread in regs; 4-way LDS reduction over q-groups at the end.
__global__ __launch_bounds__(256, 4) void pair_kernel(
    const float* __restrict__ xin, const float* __restrict__ yin,
    const float* __restrict__ FX, const float* __restrict__ FY,
    float* __restrict__ out)
{
    __shared__ float red[QG][IT][JT];      // 16 KB
    const int t  = threadIdx.x;
    const int qg = t >> 6;                 // wave index 0..3
    const int jl = t & 63;
    const int j  = blockIdx.x * JT + jl;
    const int i0 = blockIdx.y * IT;

    // Y features for this thread's 2 q's (16 floats)
    float fy[QPG * 8];
    {
        const float* fyp = FY + (size_t)j * (QMIX * 8) + qg * (QPG * 8);
#pragma unroll
        for (int k = 0; k < QPG * 8; k += 4) {
            const float4 v = *reinterpret_cast<const float4*>(fyp + k);
            fy[k + 0] = v.x; fy[k + 1] = v.y; fy[k + 2] = v.z; fy[k + 3] = v.w;
        }
    }
    const float y0 = yin[j * 3 + 0];
    const float y1 = yin[j * 3 + 1];
    const float y2 = yin[j * 3 + 2];

    const float C_EXP = -3.2259751249059600974f;  // -sqrt5 * log2(e)
    const float SQ5   = 2.2360679774997896964f;
    const float THIRD = 0.3333333333333333f;

    float acc[IT];
#pragma unroll
    for (int ii = 0; ii < IT; ++ii) acc[ii] = 0.0f;

#pragma unroll
    for (int ii = 0; ii < IT; ++ii) {
        const int i = i0 + ii;
        const float d0 = y0 - xin[i * 3 + 0];
        const float d1 = y1 - xin[i * 3 + 1];
        const float d2 = y2 - xin[i * 3 + 2];
        const float p00 = d0 * d0, p11 = d1 * d1, p22 = d2 * d2;
        const float p01 = d0 * d1, p02 = d0 * d2, p12 = d1 * d2;

        float c[QPG * 8];
        const float* cx = FX + (size_t)i * (QMIX * 8) + qg * (QPG * 8);
#pragma unroll
        for (int k = 0; k < QPG * 8; k += 4) {
            const float4 v = *reinterpret_cast<const float4*>(cx + k);
            c[k + 0] = v.x; c[k + 1] = v.y; c[k + 2] = v.z; c[k + 3] = v.w;
        }
#pragma unroll
        for (int qq = 0; qq < QPG; ++qq) {
            const float* cc = c  + qq * 8;
            const float* ff = fy + qq * 8;
            const float a0 = cc[0] + ff[0];
            const float a1 = cc[1] + ff[1];
            const float a2 = cc[2] + ff[2];
            const float a3 = cc[3] + ff[3];
            const float a4 = cc[4] + ff[4];
            const float a5 = cc[5] + ff[5];
            const float r = fmaf(a0, p00, fmaf(a1, p11, fmaf(a2, p22,
                            fmaf(a3, p01, fmaf(a4, p02, a5 * p12)))));
            const float tt   = SQ5 * r;
            const float poly = fmaf(tt, fmaf(tt, THIRD, 1.0f), 1.0f);
            const float ex   = exp2f(C_EXP * r);
            const float ct   = fmaf(cc[6], ff[6], cc[7] * ff[7]);
            acc[ii] = fmaf(poly * ex, ct, acc[ii]);
        }
    }

    // reduction over the 4 q-groups
#pragma unroll
    for (int ii = 0; ii < IT; ++ii) red[qg][ii][jl] = acc[ii];
    __syncthreads();

    const int ii2 = t >> 4;                // 0..15
    const int j2  = (t & 15) * 4;          // 0..60
    float4 s = make_float4(0.f, 0.f, 0.f, 0.f);
#pragma unroll
    for (int g2 = 0; g2 < QG; ++g2) {
        const float4 v = *reinterpret_cast<const float4*>(&red[g2][ii2][j2]);
        s.x += v.x; s.y += v.y; s.z += v.z; s.w += v.w;
    }
    float* op = out + (size_t)(i0 + ii2) * NPTS + blockIdx.x * JT + j2;
    *reinterpret_cast<float4*>(op) = s;
}

extern "C" void kernel_launch(void* const* d_in, const int* in_sizes, int n_in,
                              void* d_out, int out_size, void* d_ws, size_t ws_size,
                              hipStream_t stream) {
    const float* x  = (const float*)d_in[0];
    const float* y  = (const float*)d_in[1];
    const float* W1 = (const float*)d_in[2];
    const float* b1 = (const float*)d_in[3];
    const float* Ww = (const float*)d_in[4];
    const float* bw = (const float*)d_in[5];
    const float* Wf = (const float*)d_in[6];
    const float* bf = (const float*)d_in[7];
    const float* Ws = (const float*)d_in[8];
    const float* bs = (const float*)d_in[9];
    float* out = (float*)d_out;

    float* FX = (float*)d_ws;                       // NPTS * 64 floats
    float* FY = FX + (size_t)NPTS * (QMIX * 8);     // NPTS * 64 floats

    // features: 4096 points, 8 points per block, 80 threads per point
    feat_kernel<<<dim3((2 * NPTS) / 8), dim3(640), 0, stream>>>(
        x, y, W1, b1, Ww, bw, Wf, bf, Ws, bs, FX, FY);

    // pairwise: (32 j-blocks, 128 i-blocks)
    pair_kernel<<<dim3(NPTS / JT, NPTS / IT), dim3(256), 0, stream>>>(
        x, y, FX, FY, out);
}

// Round 3
// 40.364 us; speedup vs baseline: 1.9732x; 1.6130x over previous
//
#include <hip/hip_runtime.h>
#include <hip/hip_bf16.h>

#define NPTS 2048      // N == M == 2048
#define QMIX 8
#define LATD 64
#define IT   8         // i-rows per pair block

typedef float v2f __attribute__((ext_vector_type(2)));

__device__ __forceinline__ float softplus_f(float x) {
    return fmaxf(x, 0.0f) + log1pf(expf(-fabsf(x)));
}
__device__ __forceinline__ float selu_f(float z) {
    const float sc = 1.0507009873554805f;   // selu scale
    const float sa = 1.7580993408473766f;   // scale * alpha
    return (z > 0.0f) ? sc * z : sa * expm1f(z);
}

// Feature row layout per point (64 floats), q-pair interleaved:
//   row[qp*16 + k*2 + s]  with q = 2*qp+s, k = 0..7
//   k: [sq5*A00, sq5*A11, sq5*A22, 2sq5*A01, 2sq5*A02, 2sq5*A12, w*cos, w*sin]
// so a float4 at qp*16+2k holds {k(q0), k(q1), k+1(q0), k+1(q1)}.
__global__ __launch_bounds__(640) void feat_kernel(
    const float* __restrict__ xin, const float* __restrict__ yin,
    const float* __restrict__ W1, const float* __restrict__ b1,
    const float* __restrict__ Ww, const float* __restrict__ bw,
    const float* __restrict__ Wf, const float* __restrict__ bf,
    const float* __restrict__ Ws, const float* __restrict__ bs,
    float* __restrict__ FX, float* __restrict__ FY)
{
    __shared__ float hsh[8][LATD];   // hidden layer per local point
    __shared__ float raw[8][80];     // head outputs per local point
    const int t = threadIdx.x;

    // phase 1: h = selu(W1 @ p + b1), one (point, latent) per thread
    if (t < 512) {
        const int pl = t >> 6, l = t & 63;
        const int g = blockIdx.x * 8 + pl;
        const bool isx = (g < NPTS);
        const float* pts = isx ? (xin + 3 * g) : (yin + 3 * (g - NPTS));
        const float z = fmaf(W1[l * 3 + 0], pts[0],
                        fmaf(W1[l * 3 + 1], pts[1],
                        fmaf(W1[l * 3 + 2], pts[2], b1[l])));
        hsh[pl][l] = selu_f(z);
    }
    __syncthreads();

    // phase 2: one (point, q, head-element) per thread; dot(h, W_row) + bias
    {
        const int pl  = t / 80;
        const int rem = t % 80;
        const int q   = rem / 10;
        const int e   = rem % 10;
        const float* row;
        float acc;
        if (e == 0)      { row = Ww + q * LATD;                 acc = bw[q]; }
        else if (e <= 3) { row = Wf + (q * 3 + (e - 1)) * LATD; acc = bf[q * 3 + (e - 1)]; }
        else             { row = Ws + (q * 6 + (e - 4)) * LATD; acc = bs[q * 6 + (e - 4)]; }
#pragma unroll
        for (int l4 = 0; l4 < LATD / 4; ++l4) {
            const float4 rv = reinterpret_cast<const float4*>(row)[l4];
            const float4 hv = *reinterpret_cast<const float4*>(&hsh[pl][l4 * 4]);
            acc = fmaf(rv.x, hv.x, acc);
            acc = fmaf(rv.y, hv.y, acc);
            acc = fmaf(rv.z, hv.z, acc);
            acc = fmaf(rv.w, hv.w, acc);
        }
        raw[pl][rem] = softplus_f(acc);
    }
    __syncthreads();

    // phase 3: assemble per-(point,q) coefficients, sqrt5-folded + interleaved
    if (t < 64) {
        const int pl2 = t >> 3, q2 = t & 7;
        const int g2  = blockIdx.x * 8 + pl2;
        const bool isx2 = (g2 < NPTS);
        const float* pts2 = isx2 ? (xin + 3 * g2) : (yin + 3 * (g2 - NPTS));
        const float c0 = pts2[0], c1 = pts2[1], c2 = pts2[2];
        const float* r = raw[pl2] + q2 * 10;
        const float w  = r[0];
        const float f0 = r[1], f1 = r[2], f2 = r[3];
        const float s0 = r[4], s1 = r[5], s2 = r[6];
        const float s3 = r[7], s4 = r[8], s5 = r[9];

        // A = L L^T, L = [[s0,0,0],[s1,s2,0],[s3,s4,s5]]
        const float A00 = s0 * s0;
        const float A11 = fmaf(s1, s1, s2 * s2);
        const float A22 = fmaf(s3, s3, fmaf(s4, s4, s5 * s5));
        const float A01 = s0 * s1;
        const float A02 = s0 * s3;
        const float A12 = fmaf(s1, s3, s2 * s4);
        const float ph  = fmaf(f0, c0, fmaf(f1, c1, f2 * c2));
        float sn, cs;
        sincosf(6.283185307179586477f * ph, &sn, &cs);

        const float SQ5  = 2.2360679774997896964f;
        const float SQ52 = 2.0f * SQ5;
        float* outF = isx2 ? FX : FY;
        const int pi = isx2 ? g2 : (g2 - NPTS);
        float* o = outF + (size_t)pi * 64 + (q2 >> 1) * 16 + (q2 & 1);
        o[0]  = SQ5  * A00;
        o[2]  = SQ5  * A11;
        o[4]  = SQ5  * A22;
        o[6]  = SQ52 * A01;
        o[8]  = SQ52 * A02;
        o[10] = SQ52 * A12;
        o[12] = w * cs;
        o[14] = w * sn;
    }
}

// Pair kernel: thread owns column j and ALL 8 q (as 4 packed q-pairs).
// FX tile (IT rows) staged in LDS; xin reads wave-uniform (scalar pipe).
__global__ __launch_bounds__(256, 4) void pair_kernel(
    const float* __restrict__ xin, const float* __restrict__ yin,
    const float* __restrict__ FX, const float* __restrict__ FY,
    float* __restrict__ out)
{
    __shared__ float sFX[IT * 64];   // 2 KB
    const int t  = threadIdx.x;
    const int j  = blockIdx.x * 256 + t;
    const int i0 = blockIdx.y * IT;

    if (t < IT * 16) {
        reinterpret_cast<float4*>(sFX)[t] =
            reinterpret_cast<const float4*>(FX + (size_t)i0 * 64)[t];
    }

    // Y features -> 32 packed v2f regs
    v2f fy[32];
    {
        const float4* fp = reinterpret_cast<const float4*>(FY + (size_t)j * 64);
#pragma unroll
        for (int m = 0; m < 16; ++m) {
            const float4 v = fp[m];
            fy[m * 2 + 0] = v2f{v.x, v.y};
            fy[m * 2 + 1] = v2f{v.z, v.w};
        }
    }
    const float y0 = yin[j * 3 + 0];
    const float y1 = yin[j * 3 + 1];
    const float y2 = yin[j * 3 + 2];
    __syncthreads();

    const float C2    = -1.4426950408889634074f;  // -log2(e); exp(-t) = exp2(C2*t)
    const float THIRD = 0.3333333333333333f;

#pragma unroll
    for (int ii = 0; ii < IT; ++ii) {
        const int i = i0 + ii;
        const float d0 = y0 - xin[i * 3 + 0];
        const float d1 = y1 - xin[i * 3 + 1];
        const float d2 = y2 - xin[i * 3 + 2];
        const float p00 = d0 * d0, p11 = d1 * d1, p22 = d2 * d2;
        const float p01 = d0 * d1, p02 = d0 * d2, p12 = d1 * d2;

        const float4* cx4 = reinterpret_cast<const float4*>(sFX + ii * 64);
        v2f acc0 = v2f{0.f, 0.f}, acc1 = v2f{0.f, 0.f};
        v2f acc2 = v2f{0.f, 0.f}, acc3 = v2f{0.f, 0.f};
#pragma unroll
        for (int qp = 0; qp < 4; ++qp) {
            const float4 ca = cx4[qp * 4 + 0];   // k0,k1
            const float4 cb = cx4[qp * 4 + 1];   // k2,k3
            const float4 cc = cx4[qp * 4 + 2];   // k4,k5
            const float4 cd = cx4[qp * 4 + 3];   // k6,k7
            const v2f a0 = v2f{ca.x, ca.y} + fy[qp * 8 + 0];
            const v2f a1 = v2f{ca.z, ca.w} + fy[qp * 8 + 1];
            const v2f a2 = v2f{cb.x, cb.y} + fy[qp * 8 + 2];
            const v2f a3 = v2f{cb.z, cb.w} + fy[qp * 8 + 3];
            const v2f a4 = v2f{cc.x, cc.y} + fy[qp * 8 + 4];
            const v2f a5 = v2f{cc.z, cc.w} + fy[qp * 8 + 5];
            // tt = sqrt5 * r  (sqrt5 folded into coefficients)
            v2f tt = a0 * p00;
            tt += a1 * p11;
            tt += a2 * p22;
            tt += a3 * p01;
            tt += a4 * p02;
            tt += a5 * p12;
            const v2f poly = tt * (tt * THIRD + 1.0f) + 1.0f;
            const v2f earg = tt * C2;
            const v2f ex = v2f{__builtin_amdgcn_exp2f(earg.x),
                               __builtin_amdgcn_exp2f(earg.y)};
            v2f ct = v2f{cd.x, cd.y} * fy[qp * 8 + 6];
            ct += v2f{cd.z, cd.w} * fy[qp * 8 + 7];
            v2f upd;
            if (qp == 0)      { acc0 += (poly * ex) * ct; }
            else if (qp == 1) { acc1 += (poly * ex) * ct; }
            else if (qp == 2) { acc2 += (poly * ex) * ct; }
            else              { acc3 += (poly * ex) * ct; }
            (void)upd;
        }
        const v2f s01 = acc0 + acc1;
        const v2f s23 = acc2 + acc3;
        const v2f s = s01 + s23;
        out[(size_t)i * NPTS + j] = s.x + s.y;
    }
}

extern "C" void kernel_launch(void* const* d_in, const int* in_sizes, int n_in,
                              void* d_out, int out_size, void* d_ws, size_t ws_size,
                              hipStream_t stream) {
    const float* x  = (const float*)d_in[0];
    const float* y  = (const float*)d_in[1];
    const float* W1 = (const float*)d_in[2];
    const float* b1 = (const float*)d_in[3];
    const float* Ww = (const float*)d_in[4];
    const float* bw = (const float*)d_in[5];
    const float* Wf = (const float*)d_in[6];
    const float* bf = (const float*)d_in[7];
    const float* Ws = (const float*)d_in[8];
    const float* bs = (const float*)d_in[9];
    float* out = (float*)d_out;

    float* FX = (float*)d_ws;                       // NPTS * 64 floats
    float* FY = FX + (size_t)NPTS * 64;             // NPTS * 64 floats

    // features: 4096 points, 8 per block
    feat_kernel<<<dim3((2 * NPTS) / 8), dim3(640), 0, stream>>>(
        x, y, W1, b1, Ww, bw, Wf, bf, Ws, bs, FX, FY);

    // pairwise: (8 j-blocks of 256, 256 i-blocks of IT rows)
    pair_kernel<<<dim3(NPTS / 256, NPTS / IT), dim3(256), 0, stream>>>(
        x, y, FX, FY, out);
}